// Round 5
// baseline (109.441 us; speedup 1.0000x reference)
//
#include <hip/hip_runtime.h>

// CostVolume2D: B=8, H=256, W=512, C=32, n_disp=12, stride=1.
// cost[b,h,w,d] = sum_c |feat_l[b,h,w,c] - feat_r[b,h,w-d,c]|, feat_r zero-padded left.
//
// Block = 256 threads = half a row, 1 pixel/thread.
// feat_r tile (267 cols x 32ch) staged in LDS as plane-major SoA:
//   lds[q][colr], q = float4-quarter (0..7), colr = col - (wstart-11) in [0,266].
//   NCOL = 273 (== 1 mod 8):
//     reads  at fixed (q,d): chunk = q*273 + t + (11-d) -> lanes consecutive,
//            conflict-free (verified 0 conflicts in round 4), one base + imm offsets.
//     writes (reg-staged): 8-lane group covers all 8 bank quads (273 % 8 == 1).
// Staging global loads: lane runs are 64 consecutive float4s -> 1024 B coalesced.
//
// Round-5 fix vs round 4: no occupancy pin (LDS caps blocks/CU anyway) and
// feat_l loads moved AFTER __syncthreads so staging regs and compute regs are
// never simultaneously live -> no scratch spill (round 4: 139 MB spill writes).

constexpr int Wd   = 512;
constexpr int ND   = 12;
constexpr int NCOL = 273;             // 267 + pad, == 1 mod 8
constexpr int NCHUNK = 8 * NCOL;      // 2184 chunks = 34944 B
constexpr int NSRC = 267 * 8;         // 2136 source chunks per tile

__device__ __forceinline__ float l1_4(float4 a, float4 b) {
    return fabsf(a.x - b.x) + fabsf(a.y - b.y) + fabsf(a.z - b.z) + fabsf(a.w - b.w);
}

__global__ __launch_bounds__(256) void cost_volume_kernel(
    const float* __restrict__ fl,
    const float* __restrict__ fr,
    float* __restrict__ out)
{
    __shared__ float4 lds4[NCHUNK];

    const int t    = threadIdx.x;
    const int wave = t >> 6;
    const int lane = t & 63;
    const int wstart = (blockIdx.x & 1) * 256;
    const int bh     = blockIdx.x >> 1;            // b*H + h
    const float4* fr_row4 = reinterpret_cast<const float4*>(fr + (size_t)bh * Wd * 32);

    // ---- stage: coalesced global loads into registers, then permuted ds_writes
    float4 streg[9];
    #pragma unroll
    for (int it = 0; it < 9; ++it) {
        const int r = it * 4 + wave;
        if (r < 34) {
            const int ss   = min(r * 64 + lane, NSRC - 1);   // clamp tail
            const int colr = ss >> 3;
            const int q    = ss & 7;
            int col = wstart - 11 + colr;
            col = max(col, 0);                    // left-edge clamp; content don't-care
            streg[it] = fr_row4[col * 8 + q];
        }
    }

    #pragma unroll
    for (int it = 0; it < 9; ++it) {
        const int r = it * 4 + wave;
        if (r < 34) {
            const int ss   = min(r * 64 + lane, NSRC - 1);
            const int colr = ss >> 3;
            const int q    = ss & 7;
            lds4[q * NCOL + colr] = streg[it];
        }
    }

    __syncthreads();

    // ---- feat_l[b,h,w,:] into registers (after barrier: keeps reg pressure low)
    const int w = wstart + t;
    const size_t pix = (size_t)bh * Wd + w;
    const float4* lp = reinterpret_cast<const float4*>(fl) + pix * 8;
    float4 L[8];
    #pragma unroll
    for (int q = 0; q < 8; ++q) L[q] = lp[q];

    float lsum = 0.f;
    #pragma unroll
    for (int q = 0; q < 8; ++q)
        lsum += fabsf(L[q].x) + fabsf(L[q].y) + fabsf(L[q].z) + fabsf(L[q].w);

    // ---- 12 disparities from LDS: per q one base, 12 imm-offset ds_read_b128
    float res[ND];
    #pragma unroll
    for (int d = 0; d < ND; ++d) res[d] = 0.f;

    #pragma unroll
    for (int q = 0; q < 8; ++q) {
        const float4 Lq = L[q];
        const float4* base = &lds4[q * NCOL + t];   // colr = t + (11-d)
        #pragma unroll
        for (int d = 0; d < ND; ++d) {
            res[d] += l1_4(Lq, base[11 - d]);
        }
    }

    // ---- left edge: w < d -> feat_r fully shifted out (zeros) -> sum|feat_l|
    #pragma unroll
    for (int d = 0; d < ND; ++d)
        if (w < d) res[d] = lsum;

    float4* op = reinterpret_cast<float4*>(out + pix * ND);
    op[0] = make_float4(res[0], res[1], res[2],  res[3]);
    op[1] = make_float4(res[4], res[5], res[6],  res[7]);
    op[2] = make_float4(res[8], res[9], res[10], res[11]);
}

extern "C" void kernel_launch(void* const* d_in, const int* in_sizes, int n_in,
                              void* d_out, int out_size, void* d_ws, size_t ws_size,
                              hipStream_t stream)
{
    const float* fl = (const float*)d_in[0];
    const float* fr = (const float*)d_in[1];
    float* out = (float*)d_out;

    const int grid = 8 * 256 * 2;                // (b,h) x 2 half-rows
    cost_volume_kernel<<<grid, 256, 0, stream>>>(fl, fr, out);
}

// Round 7
// 57.813 us; speedup vs baseline: 1.8930x; 1.8930x over previous
//
#include <hip/hip_runtime.h>

// CostVolume2D: B=8, H=256, W=512, C=32, n_disp=12, stride=1.
// cost[b,h,w,d] = sum_c |feat_l[b,h,w,c] - feat_r[b,h,w-d,c]|, feat_r zero-padded left.
//
// Block = 256 threads = half a row, 1 pixel/thread.
// feat_r tile (267 cols x 32ch) lives in LDS plane-major: lds4[q][colr],
//   q = float4-quarter (0..7), colr = col - (wstart-11) in [0,266], NCOL=272.
// Staged DIRECTLY by global_load_lds (no register staging -> no spill, the
//   round-4/5 failure): dest = 64 lane-consecutive chunks of one plane (legal
//   linear glld dest), source = per-lane col*128B + q*16B (128B-stride scatter;
//   sibling q-planes of the same col window consume the remaining line sectors
//   from L1/L2, so HBM fetch stays ~compulsory).
// Reads: fixed (q,d) -> lane-consecutive chunks (measured 0-conflict in r4/r5),
//   one base per q + 12 immediate offsets.
// Output stores nontemporal (via native ext_vector_type — HIP float4 class is
//   rejected by the builtin): keep the inputs resident in L3.

constexpr int Wd   = 512;
constexpr int ND   = 12;
constexpr int NCOL = 272;             // per-plane chunk capacity (267 used)

typedef float vfloat4 __attribute__((ext_vector_type(4)));

__device__ __forceinline__ float l1_4(float4 a, float4 b) {
    return fabsf(a.x - b.x) + fabsf(a.y - b.y) + fabsf(a.z - b.z) + fabsf(a.w - b.w);
}

__global__ __launch_bounds__(256) void cost_volume_kernel(
    const float* __restrict__ fl,
    const float* __restrict__ fr,
    float* __restrict__ out)
{
    __shared__ float4 lds4[8 * NCOL];          // 34816 B

    const int t    = threadIdx.x;
    const int wave = t >> 6;
    const int lane = t & 63;
    const int wstart = (blockIdx.x & 1) * 256;
    const int bh     = blockIdx.x >> 1;        // b*H + h
    const float* fr_row = fr + (size_t)bh * Wd * 32;

    // ---- stage feat_r directly into plane-major LDS.
    // wave w stages planes {2w, 2w+1}; 5 col-runs of 64 lanes (last run: 11 lanes).
    const int q0 = 2 * wave;
    #pragma unroll
    for (int run = 0; run < 5; ++run) {
        const int colr = run * 64 + lane;
        int col = wstart - 11 + colr;
        col = max(col, 0);                     // guard cols: clamped, never used
        if (run < 4 || lane < 267 - 256) {     // 267 cols total
            #pragma unroll
            for (int dq = 0; dq < 2; ++dq) {
                const int q = q0 + dq;
                __builtin_amdgcn_global_load_lds(
                    (const __attribute__((address_space(1))) void*)(fr_row + (size_t)col * 32 + q * 4),
                    (__attribute__((address_space(3))) void*)(lds4 + q * NCOL + run * 64 + lane),
                    16, 0, 0);
            }
        }
    }

    // ---- feat_l[b,h,w,:] into registers (issued under staging latency;
    //       this is the round-2 structure that did NOT spill: no staging array).
    const int w = wstart + t;
    const size_t pix = (size_t)bh * Wd + w;
    const float4* lp = reinterpret_cast<const float4*>(fl) + pix * 8;
    float4 L[8];
    #pragma unroll
    for (int q = 0; q < 8; ++q) L[q] = lp[q];

    float lsum = 0.f;
    #pragma unroll
    for (int q = 0; q < 8; ++q)
        lsum += fabsf(L[q].x) + fabsf(L[q].y) + fabsf(L[q].z) + fabsf(L[q].w);

    __syncthreads();                           // drains glld (vmcnt) + visibility

    // ---- 12 disparities: per q one LDS base, 12 imm-offset ds_read_b128,
    //      lane-consecutive addresses (0-conflict pattern, verified r4/r5).
    float res[ND];
    #pragma unroll
    for (int d = 0; d < ND; ++d) res[d] = 0.f;

    #pragma unroll
    for (int q = 0; q < 8; ++q) {
        const float4 Lq = L[q];
        const float4* base = &lds4[q * NCOL + t];   // colr = t + (11-d)
        #pragma unroll
        for (int d = 0; d < ND; ++d) {
            res[d] += l1_4(Lq, base[11 - d]);
        }
    }

    // ---- left edge: w < d -> feat_r fully shifted out (zeros) -> sum|feat_l|
    #pragma unroll
    for (int d = 0; d < ND; ++d)
        if (w < d) res[d] = lsum;

    // ---- nontemporal output stores (don't evict inputs from L3)
    vfloat4* op = reinterpret_cast<vfloat4*>(out + pix * ND);
    vfloat4 o0 = {res[0], res[1], res[2],  res[3]};
    vfloat4 o1 = {res[4], res[5], res[6],  res[7]};
    vfloat4 o2 = {res[8], res[9], res[10], res[11]};
    __builtin_nontemporal_store(o0, op + 0);
    __builtin_nontemporal_store(o1, op + 1);
    __builtin_nontemporal_store(o2, op + 2);
}

extern "C" void kernel_launch(void* const* d_in, const int* in_sizes, int n_in,
                              void* d_out, int out_size, void* d_ws, size_t ws_size,
                              hipStream_t stream)
{
    const float* fl = (const float*)d_in[0];
    const float* fr = (const float*)d_in[1];
    float* out = (float*)d_out;

    const int grid = 8 * 256 * 2;              // (b,h) x 2 half-rows
    cost_volume_kernel<<<grid, 256, 0, stream>>>(fl, fr, out);
}